// Round 1
// baseline (439.867 us; speedup 1.0000x reference)
//
#include <hip/hip_runtime.h>

// Binarized depthwise 3x3 conv, stride 1, SAME, NHWC.
// x: (16,112,112,256) f32, kernel: (3,3,256,1) f32, out: (16,112,112,256) f32.
// out[n,h,w,c] = sum_{dh,dw valid} sign(x[n,h+dh,w+dw,c]) * sign(k[dh+1,dw+1,c])
// sign(a)=+1 if a>=0 else -1; product computed as sign-bit XOR -> +-1.0f.

constexpr int N = 16, H = 112, W = 112, C = 256;

__global__ __launch_bounds__(256) void bsign_dw3x3(
        const float* __restrict__ x,
        const float* __restrict__ k,
        float* __restrict__ out) {
    // Block = 256 threads = 4 waves; each wave owns one pixel (64 lanes x 4ch = 256 ch).
    const int cg = threadIdx.x & 63;        // channel group within pixel
    const int wq = threadIdx.x >> 6;        // wave index -> pixel within block
    const int w  = blockIdx.x * 4 + wq;
    const int h  = blockIdx.y;
    const int n  = blockIdx.z;
    const int c0 = cg << 2;                 // first of 4 channels

    // Kernel sign bits per tap t = (kh*3+kw), layout k[t*C + c]. 9 KB total -> L1 resident.
    unsigned int ks[9][4];
#pragma unroll
    for (int t = 0; t < 9; ++t) {
        const uint4 kv = *reinterpret_cast<const uint4*>(k + t * C + c0);
        ks[t][0] = kv.x;
        ks[t][1] = kv.y;
        ks[t][2] = kv.z;
        ks[t][3] = kv.w;
    }

    const float* xn = x + (size_t)n * (H * W * C);
    float a0 = 0.f, a1 = 0.f, a2 = 0.f, a3 = 0.f;

#pragma unroll
    for (int dh = -1; dh <= 1; ++dh) {
        const int hh = h + dh;
        if (hh < 0 || hh >= H) continue;            // wave-uniform (h is per-block)
#pragma unroll
        for (int dw = -1; dw <= 1; ++dw) {
            const int ww = w + dw;
            if (ww < 0 || ww >= W) continue;        // wave-uniform (w is per-wave)
            const uint4 xv = *reinterpret_cast<const uint4*>(
                xn + ((size_t)hh * W + ww) * C + c0);
            const unsigned int* kb = ks[(dh + 1) * 3 + (dw + 1)];
            // +-1.0f from xor of sign bits
            a0 += __uint_as_float(((xv.x ^ kb[0]) & 0x80000000u) | 0x3f800000u);
            a1 += __uint_as_float(((xv.y ^ kb[1]) & 0x80000000u) | 0x3f800000u);
            a2 += __uint_as_float(((xv.z ^ kb[2]) & 0x80000000u) | 0x3f800000u);
            a3 += __uint_as_float(((xv.w ^ kb[3]) & 0x80000000u) | 0x3f800000u);
        }
    }

    float4 o = make_float4(a0, a1, a2, a3);
    *reinterpret_cast<float4*>(out + (((size_t)n * H + h) * W + w) * C + c0) = o;
}

extern "C" void kernel_launch(void* const* d_in, const int* in_sizes, int n_in,
                              void* d_out, int out_size, void* d_ws, size_t ws_size,
                              hipStream_t stream) {
    const float* x = (const float*)d_in[0];   // (16,112,112,256) f32
    const float* k = (const float*)d_in[1];   // (3,3,256,1) f32
    float* out = (float*)d_out;               // (16,112,112,256) f32

    dim3 grid(W / 4, H, N);                   // (28, 112, 16)
    bsign_dw3x3<<<grid, 256, 0, stream>>>(x, k, out);
}

// Round 2
// 384.216 us; speedup vs baseline: 1.1448x; 1.1448x over previous
//
#include <hip/hip_runtime.h>

// Binarized depthwise 3x3 conv, stride 1, SAME, NHWC, sign(0)=+1.
// x: (16,112,112,256) f32, kernel: (3,3,256,1) f32, out: (16,112,112,256) f32.
//
// Register-blocked sliding window along W. Each wave: one (n,h) row strip of
// TW outputs, 64 lanes x 4 channels = all 256 channels. Per x column, compute
// d_j[col] = NROWS + 2 * sum_rows((x>>31)^(k>>31))   (j = kernel column)
// (each valid tap contributes +-1 = 1 + 2*b, b in {0,-1}).
// out(w) = d0[w-1] + d1[w] + d2[w+1]; out-of-range columns contribute 0,
// so W-border needs no special-casing beyond pipeline init. H-border via
// 3 template variants (wave-uniform).

constexpr int N = 16, H = 112, W = 112, C = 256;
constexpr int TW = 28;   // outputs per wave strip; W/TW = 4 strips per row

struct I4 { int v[4]; };

__device__ __forceinline__ I4 load4i(const float* p) {
    const int4 t = *reinterpret_cast<const int4*>(p);
    I4 r; r.v[0] = t.x; r.v[1] = t.y; r.v[2] = t.z; r.v[3] = t.w;
    return r;
}

template<bool TOP, bool BOT>
__device__ __forceinline__ void run_strip(
        const float* __restrict__ x, const float* __restrict__ k,
        float* __restrict__ out, int n, int h, int w0, int c0) {

    constexpr int NROWS = 1 + (TOP ? 1 : 0) + (BOT ? 1 : 0);

    // Kernel sign masks km[r][j][ch] = 0 or -1 (arith shift). 36 VGPRs, L1-fed.
    int km[3][3][4];
#pragma unroll
    for (int r = 0; r < 3; ++r)
#pragma unroll
        for (int j = 0; j < 3; ++j) {
            const int4 kv = *reinterpret_cast<const int4*>(k + (r * 3 + j) * C + c0);
            km[r][j][0] = kv.x >> 31; km[r][j][1] = kv.y >> 31;
            km[r][j][2] = kv.z >> 31; km[r][j][3] = kv.w >> 31;
        }

    const size_t rowstride = (size_t)W * C;
    const float* rc = x + (size_t)(n * H + h) * rowstride + c0;
    const float* rm = rc - rowstride;   // only dereferenced if TOP
    const float* rp = rc + rowstride;   // only dereferenced if BOT
    float* orow = out + (size_t)(n * H + h) * rowstride + c0;

    // Compute d_j (j=0..2) for 4 channels at column cc.
    auto colD = [&](int cc, int dj[3][4]) {
        I4 xm, xc, xp;
        if (TOP) xm = load4i(rm + (size_t)cc * C);
        xc = load4i(rc + (size_t)cc * C);
        if (BOT) xp = load4i(rp + (size_t)cc * C);
#pragma unroll
        for (int ch = 0; ch < 4; ++ch) {
            const int am = TOP ? (xm.v[ch] >> 31) : 0;
            const int ac = xc.v[ch] >> 31;
            const int ap = BOT ? (xp.v[ch] >> 31) : 0;
#pragma unroll
            for (int j = 0; j < 3; ++j) {
                int s = ac ^ km[1][j][ch];
                if (TOP) s += am ^ km[0][j][ch];
                if (BOT) s += ap ^ km[2][j][ch];
                dj[j][ch] = NROWS + 2 * s;
            }
        }
    };

    int d0_m2[4], d0_m1[4], d1_m1[4];

    // Prologue: column w0-1 (only d0 needed) and column w0 (d0, d1).
    if (w0 > 0) {
        int dj[3][4]; colD(w0 - 1, dj);
#pragma unroll
        for (int ch = 0; ch < 4; ++ch) d0_m2[ch] = dj[0][ch];
    } else {
#pragma unroll
        for (int ch = 0; ch < 4; ++ch) d0_m2[ch] = 0;
    }
    {
        int dj[3][4]; colD(w0, dj);
#pragma unroll
        for (int ch = 0; ch < 4; ++ch) { d0_m1[ch] = dj[0][ch]; d1_m1[ch] = dj[1][ch]; }
    }

    // Main loop: columns cc = w0+1 .. w0+TW-1 (all in-range), emit w = cc-1.
#pragma unroll 3
    for (int i = 1; i < TW; ++i) {
        const int cc = w0 + i;
        int dj[3][4]; colD(cc, dj);
        float ov[4];
#pragma unroll
        for (int ch = 0; ch < 4; ++ch) {
            ov[ch] = (float)(d0_m2[ch] + d1_m1[ch] + dj[2][ch]);
            d0_m2[ch] = d0_m1[ch]; d0_m1[ch] = dj[0][ch]; d1_m1[ch] = dj[1][ch];
        }
        *reinterpret_cast<float4*>(orow + (size_t)(cc - 1) * C) =
            make_float4(ov[0], ov[1], ov[2], ov[3]);
    }

    // Epilogue: emit w = w0+TW-1 using column cc = w0+TW (absent if == W).
    {
        const int cc = w0 + TW;
        int d2v[4] = {0, 0, 0, 0};
        if (cc < W) {
            int dj[3][4]; colD(cc, dj);
#pragma unroll
            for (int ch = 0; ch < 4; ++ch) d2v[ch] = dj[2][ch];
        }
        float ov[4];
#pragma unroll
        for (int ch = 0; ch < 4; ++ch) ov[ch] = (float)(d0_m2[ch] + d1_m1[ch] + d2v[ch]);
        *reinterpret_cast<float4*>(orow + (size_t)(cc - 1) * C) =
            make_float4(ov[0], ov[1], ov[2], ov[3]);
    }
}

__global__ __launch_bounds__(256) void bsign_dw3x3_strip(
        const float* __restrict__ x, const float* __restrict__ k,
        float* __restrict__ out) {
    const int c0 = (threadIdx.x & 63) << 2;      // 4 channels per lane
    const int wq = threadIdx.x >> 6;             // wave within block -> h offset
    const int h  = blockIdx.y * 4 + wq;          // 4 adjacent rows per block (L2 reuse)
    const int w0 = blockIdx.x * TW;
    const int n  = blockIdx.z;

    if (h == 0)            run_strip<false, true >(x, k, out, n, h, w0, c0);
    else if (h == H - 1)   run_strip<true,  false>(x, k, out, n, h, w0, c0);
    else                   run_strip<true,  true >(x, k, out, n, h, w0, c0);
}

extern "C" void kernel_launch(void* const* d_in, const int* in_sizes, int n_in,
                              void* d_out, int out_size, void* d_ws, size_t ws_size,
                              hipStream_t stream) {
    const float* x = (const float*)d_in[0];   // (16,112,112,256) f32
    const float* k = (const float*)d_in[1];   // (3,3,256,1) f32
    float* out = (float*)d_out;               // (16,112,112,256) f32

    dim3 grid(W / TW, H / 4, N);              // (4, 28, 16)
    bsign_dw3x3_strip<<<grid, 256, 0, stream>>>(x, k, out);
}

// Round 4
// 350.782 us; speedup vs baseline: 1.2540x; 1.0953x over previous
//
#include <hip/hip_runtime.h>

// Binarized depthwise 3x3 conv, stride 1, SAME, NHWC, sign(0)=+1.
// x: (16,112,112,256) f32, kernel: (3,3,256,1) f32, out: (16,112,112,256) f32.
//
// Sliding-window column factoring (round 2) + bit-packed sign codes (round 3):
// per channel, kernel signs packed as 9-bit code kb (bit 3*r+j = sign k[r][j]).
// Per x column, xcode = sign bits of rows (h-1,h,h+1) at bits {0,3,6}.
// cnt_j = popc(xcode ^ kbj[j])  (kbj pre-shifted+masked), d_j = NROWS-2*cnt_j.
// out(w) = d0[w-1] + d1[w] + d2[w+1]; missing columns contribute 0.
// Invalid rows (image border) are masked out of kbj at compile time per
// template variant, so xcode simply omits those bits.

constexpr int N = 16, H = 112, W = 112, C = 256;
constexpr int TW = 16;   // outputs per wave strip; W/TW = 7 strips per row

// Native clang vector type: __builtin_nontemporal_store requires it
// (HIP's float4 is a struct and is rejected).
typedef float f32x4 __attribute__((ext_vector_type(4)));

template<bool TOP, bool BOT>
__device__ __forceinline__ void run_strip(
        const float* __restrict__ x, const float* __restrict__ k,
        float* __restrict__ out, int n, int h, int w0, int c0) {

    constexpr unsigned VMASK = (TOP ? 0x1u : 0u) | 0x8u | (BOT ? 0x40u : 0u);
    constexpr int NROWS = (TOP ? 1 : 0) + 1 + (BOT ? 1 : 0);

    // Packed kernel sign codes, pre-shifted per kernel column j. 12 VGPRs.
    unsigned kb[4] = {0u, 0u, 0u, 0u};
#pragma unroll
    for (int t = 0; t < 9; ++t) {
        const uint4 kv = *reinterpret_cast<const uint4*>(k + t * C + c0);
        kb[0] |= (kv.x >> 31) << t;
        kb[1] |= (kv.y >> 31) << t;
        kb[2] |= (kv.z >> 31) << t;
        kb[3] |= (kv.w >> 31) << t;
    }
    unsigned kbj[3][4];
#pragma unroll
    for (int j = 0; j < 3; ++j)
#pragma unroll
        for (int ch = 0; ch < 4; ++ch)
            kbj[j][ch] = (kb[ch] >> j) & 0x49u & VMASK;

    const size_t rowstride = (size_t)W * C;
    const float* rc = x + (size_t)(n * H + h) * rowstride + c0;
    const float* rm = rc - rowstride;   // only touched if TOP
    const float* rp = rc + rowstride;   // only touched if BOT
    float* orow = out + (size_t)(n * H + h) * rowstride + c0;

    // d_j (j=0..2) for 4 channels at column cc.
    auto colD = [&](int cc, int dj[3][4]) {
        uint4 xm = make_uint4(0,0,0,0), xp = make_uint4(0,0,0,0);
        if constexpr (TOP) xm = *reinterpret_cast<const uint4*>(rm + (size_t)cc * C);
        const uint4 xc = *reinterpret_cast<const uint4*>(rc + (size_t)cc * C);
        if constexpr (BOT) xp = *reinterpret_cast<const uint4*>(rp + (size_t)cc * C);

        unsigned xcode[4];
        {
            const unsigned* m = &xm.x; const unsigned* c = &xc.x; const unsigned* p = &xp.x;
#pragma unroll
            for (int ch = 0; ch < 4; ++ch) {
                unsigned r = (c[ch] >> 31) << 3;
                if constexpr (TOP) r |= (m[ch] >> 31);
                if constexpr (BOT) r |= (p[ch] >> 31) << 6;
                xcode[ch] = r;
            }
        }
#pragma unroll
        for (int ch = 0; ch < 4; ++ch)
#pragma unroll
            for (int j = 0; j < 3; ++j)
                dj[j][ch] = NROWS - 2 * __popc(xcode[ch] ^ kbj[j][ch]);
    };

    int d0_m2[4], d0_m1[4], d1_m1[4];

    // Prologue: column w0-1 (only d0 used) and column w0 (d0, d1).
    if (w0 > 0) {
        int dj[3][4]; colD(w0 - 1, dj);
#pragma unroll
        for (int ch = 0; ch < 4; ++ch) d0_m2[ch] = dj[0][ch];
    } else {
#pragma unroll
        for (int ch = 0; ch < 4; ++ch) d0_m2[ch] = 0;
    }
    {
        int dj[3][4]; colD(w0, dj);
#pragma unroll
        for (int ch = 0; ch < 4; ++ch) { d0_m1[ch] = dj[0][ch]; d1_m1[ch] = dj[1][ch]; }
    }

    // Main loop: columns cc = w0+1 .. w0+TW-1 (all in-range), emit w = cc-1.
#pragma unroll 3
    for (int i = 1; i < TW; ++i) {
        const int cc = w0 + i;
        int dj[3][4]; colD(cc, dj);
        f32x4 ov;
#pragma unroll
        for (int ch = 0; ch < 4; ++ch) {
            ov[ch] = (float)(d0_m2[ch] + d1_m1[ch] + dj[2][ch]);
            d0_m2[ch] = d0_m1[ch]; d0_m1[ch] = dj[0][ch]; d1_m1[ch] = dj[1][ch];
        }
        __builtin_nontemporal_store(ov,
            reinterpret_cast<f32x4*>(orow + (size_t)(cc - 1) * C));
    }

    // Epilogue: emit w = w0+TW-1 using column cc = w0+TW (absent if == W).
    {
        const int cc = w0 + TW;
        int d2v[4] = {0, 0, 0, 0};
        if (cc < W) {
            int dj[3][4]; colD(cc, dj);
#pragma unroll
            for (int ch = 0; ch < 4; ++ch) d2v[ch] = dj[2][ch];
        }
        f32x4 ov;
#pragma unroll
        for (int ch = 0; ch < 4; ++ch) ov[ch] = (float)(d0_m2[ch] + d1_m1[ch] + d2v[ch]);
        __builtin_nontemporal_store(ov,
            reinterpret_cast<f32x4*>(orow + (size_t)(cc - 1) * C));
    }
}

__global__ __launch_bounds__(256) void bsign_dw3x3_pop(
        const float* __restrict__ x, const float* __restrict__ k,
        float* __restrict__ out) {
    const int c0 = (threadIdx.x & 63) << 2;      // 4 channels per lane
    const int wq = threadIdx.x >> 6;             // wave within block -> h offset
    const int h  = blockIdx.y * 4 + wq;          // 4 adjacent rows per block
    const int w0 = blockIdx.x * TW;
    const int n  = blockIdx.z;

    if (h == 0)            run_strip<false, true >(x, k, out, n, h, w0, c0);
    else if (h == H - 1)   run_strip<true,  false>(x, k, out, n, h, w0, c0);
    else                   run_strip<true,  true >(x, k, out, n, h, w0, c0);
}

extern "C" void kernel_launch(void* const* d_in, const int* in_sizes, int n_in,
                              void* d_out, int out_size, void* d_ws, size_t ws_size,
                              hipStream_t stream) {
    const float* x = (const float*)d_in[0];   // (16,112,112,256) f32
    const float* k = (const float*)d_in[1];   // (3,3,256,1) f32
    float* out = (float*)d_out;               // (16,112,112,256) f32

    dim3 grid(W / TW, H / 4, N);              // (7, 28, 16)
    bsign_dw3x3_pop<<<grid, 256, 0, stream>>>(x, k, out);
}